// Round 8
// baseline (401.062 us; speedup 1.0000x reference)
//
#include <hip/hip_runtime.h>
#include <hip/hip_bf16.h>

#define N_NODES 100000
#define N_EDGES 1600000
#define F_IN 128
#define HID 64
#define N_GRAPHS 1024

// fine dst-partition: bucket = dst>>9 (512 nodes/bucket)
#define SH 9
#define NBU 196        // buckets used: ceil(100000/512)
#define NB 200         // allocated
#define BCAP 9728      // mean 8192 + 17 sigma
#define EPB 8192       // edges per k_part block (196 blocks exactly)
#define NSLICE 2       // 2 slices x 32 feats (64-B rows): one cache line per edge-slice request

typedef __attribute__((ext_vector_type(8))) short bf16x8;
typedef __attribute__((ext_vector_type(4))) float f32x4;
typedef __attribute__((ext_vector_type(4))) unsigned int u32x4;

// ---------------- bf16 bit helpers --------------------------------------------
__device__ __forceinline__ unsigned short f2bf(float f) {
    __hip_bfloat16 h = __float2bfloat16(f);   // RNE
    return *reinterpret_cast<unsigned short*>(&h);
}
__device__ __forceinline__ float bf2f(unsigned int u) {
    return __uint_as_float(u << 16);
}

// ---------------- dual-path load helpers (wire dtype resolved at runtime) -----
__device__ __forceinline__ float loadf(const void* p, size_t i, int f32) {
    if (f32) return ((const float*)p)[i];
    return __bfloat162float(((const __hip_bfloat16*)p)[i]);
}
__device__ __forceinline__ int loadi(const void* p, size_t i, int i64) {
    if (i64) return (int)((const long long*)p)[i];
    return ((const int*)p)[i];
}

// ---------------- init: wire detect + zero small counters ---------------------
__global__ void k_init(const unsigned int* __restrict__ xw_,
                       const unsigned int* __restrict__ ei_,
                       int* __restrict__ flags,
                       int* __restrict__ gcnt, int* __restrict__ bcnt) {
    __shared__ int cnt_f, cnt_i;
    int t = threadIdx.x;
    if (t == 0) { cnt_f = 0; cnt_i = 0; }
    __syncthreads();
    unsigned int w = xw_[t];
    unsigned int e = (w >> 7) & 0xFFu;
    if (e >= 100u && e <= 140u) atomicAdd(&cnt_f, 1);
    unsigned int iw = ei_[2 * t + 1];
    if (iw == 0u) atomicAdd(&cnt_i, 1);
    for (int i = t; i < N_GRAPHS; i += 256) gcnt[i] = 0;
    for (int i = t; i < NB; i += 256) bcnt[i] = 0;
    __syncthreads();
    if (t == 0) {
        flags[0] = (cnt_f < 180) ? 1 : 0;   // 1 => fp32 wire
        flags[1] = (cnt_i >= 128) ? 1 : 0;  // 1 => int64 wire
    }
}

// ---------------- phase A: partition by dst>>9, two-pass fat blocks -----------
// R4: pass 1 stages packed word + bucket id in LDS; pass 2 re-reads LDS instead
// of re-reading edge_index from global (-12.8 MB int64 traffic, -1.6M decodes).
__global__ __launch_bounds__(256) void k_part(const void* __restrict__ ei,
                                              const void* __restrict__ batch,
                                              int* __restrict__ bcnt,
                                              int* __restrict__ gcnt,
                                              unsigned int* __restrict__ packed,
                                              const int* __restrict__ flags) {
    int I64 = flags[1];
    __shared__ int hist[NB];
    __shared__ int base[NB];
    __shared__ int ghist[N_GRAPHS];        // 4 KB
    __shared__ unsigned int elds[EPB];     // 32 KB: packed words
    __shared__ unsigned char ebkt[EPB];    // 8 KB: bucket ids (0xFF = invalid)
    int t = threadIdx.x;
    if (t < NB) hist[t] = 0;
    for (int i = t; i < N_GRAPHS; i += 256) ghist[i] = 0;
    __syncthreads();
    // batch counting: block covers nodes [blk*512, blk*512+512)
    for (int it = 0; it < 2; ++it) {
        int n = blockIdx.x * 512 + it * 256 + t;
        if (n < N_NODES) atomicAdd(&ghist[loadi(batch, n, I64)], 1);
    }
    // edge pass 1: decode once, stage in LDS, bucket counts
    int e0 = blockIdx.x * EPB;
#pragma unroll 4
    for (int it = 0; it < EPB / 256; ++it) {
        int idx = it * 256 + t;
        int e = e0 + idx;
        unsigned int pv = 0u;
        unsigned char bk = 0xFFu;
        if (e < N_EDGES) {
            int sN = loadi(ei, e, I64);
            int d = loadi(ei, (size_t)N_EDGES + e, I64);
            bk = (unsigned char)(d >> SH);
            pv = ((unsigned int)sN << SH) | (unsigned int)(d & 511);
            atomicAdd(&hist[d >> SH], 1);
        }
        elds[idx] = pv;
        ebkt[idx] = bk;
    }
    __syncthreads();
    if (t < NB) {
        base[t] = hist[t] ? atomicAdd(&bcnt[t], hist[t]) : 0;
        hist[t] = 0;   // reuse as pass-2 rank counter
    }
    for (int i = t; i < N_GRAPHS; i += 256)
        if (ghist[i]) atomicAdd(&gcnt[i], ghist[i]);
    __syncthreads();
    // edge pass 2: rank + write from LDS
#pragma unroll 4
    for (int it = 0; it < EPB / 256; ++it) {
        int idx = it * 256 + t;
        unsigned char bk = ebkt[idx];
        if (bk != 0xFFu) {
            unsigned int pv = elds[idx];
            int r = atomicAdd(&hist[bk], 1);
            int pos = base[bk] + r;
            if (pos < BCAP)
                packed[(size_t)bk * BCAP + pos] = pv;
        }
    }
}

// ---------------- hist: in-degree + dis + scan partials (fused) ---------------
__global__ __launch_bounds__(256) void k_hist(const unsigned int* __restrict__ packed,
                                              const int* __restrict__ bcnt,
                                              int* __restrict__ cnt,
                                              float* __restrict__ dis,
                                              int* __restrict__ partN) {
    __shared__ int hist[512];
    int b = blockIdx.x;
    int t = threadIdx.x;
    int n = bcnt[b];
    if (n > BCAP) n = BCAP;
    for (int i = t; i < 512; i += 256) hist[i] = 0;
    __syncthreads();
    const unsigned int* pb = packed + (size_t)b * BCAP;
    for (int i = t; i < n; i += 256)
        atomicAdd(&hist[pb[i] & 511u], 1);
    __syncthreads();
    int nbase = b << SH;
    for (int i = t; i < 512; i += 256) {
        int node = nbase + i;
        if (node < N_NODES) {
            int c = hist[i];
            cnt[node] = c;
            dis[node] = rsqrtf((float)c + 1.0f);
        }
    }
    __syncthreads();
    for (int off = 128; off > 0; off >>= 1) {
        if (t < off) { hist[t] += hist[t + off]; hist[256 + t] += hist[256 + t + off]; }
        __syncthreads();
    }
    if (t == 0) {
        partN[2 * b] = hist[0];
        if (2 * b + 1 < 391) partN[2 * b + 1] = hist[256];
    }
}

// ---------------- middle scan: partN (391) + graph scan (1024), one block -----
__global__ void k_scan_mid(int* __restrict__ partial, int nb,
                           int* __restrict__ rp, int n,
                           const int* __restrict__ gcnt, int* __restrict__ gptr) {
    __shared__ int s[512];
    int t = threadIdx.x;
    int v = (t < nb) ? partial[t] : 0;
    s[t] = v;
    __syncthreads();
    for (int off = 1; off < 512; off <<= 1) {
        int x = (t >= off) ? s[t - off] : 0;
        __syncthreads();
        s[t] += x;
        __syncthreads();
    }
    if (t < nb) partial[t] = s[t] - v;   // exclusive
    if (t == 511) rp[n] = s[511];        // grand total
    __syncthreads();
    int a = gcnt[2 * t], bq = gcnt[2 * t + 1];
    int ps = a + bq;
    s[t] = ps;
    __syncthreads();
    for (int off = 1; off < 512; off <<= 1) {
        int x = (t >= off) ? s[t - off] : 0;
        __syncthreads();
        s[t] += x;
        __syncthreads();
    }
    int excl = s[t] - ps;
    gptr[2 * t] = excl;
    gptr[2 * t + 1] = excl + a;
    if (t == 511) gptr[1024] = s[511];
}

// ---------------- scan p3: per-256-chunk local scan + offset -> rp ------------
__global__ void k_scan_p3(const int* __restrict__ in, const int* __restrict__ partial,
                          int* __restrict__ out, int n) {
    __shared__ int s[256];
    int t = threadIdx.x;
    int i = blockIdx.x * 256 + t;
    int v = (i < n) ? in[i] : 0;
    s[t] = v;
    __syncthreads();
    for (int off = 1; off < 256; off <<= 1) {
        int x = (t >= off) ? s[t - off] : 0;
        __syncthreads();
        s[t] += x;
        __syncthreads();
    }
    if (i < n) out[i] = partial[blockIdx.x] + s[t] - v;
}

// ---------------- phase B: LDS counting-sort, dense csr writes ----------------
__global__ __launch_bounds__(512) void k_bucketcsr(const unsigned int* __restrict__ packed,
                                                   const int* __restrict__ bcnt,
                                                   const int* __restrict__ rp,
                                                   int* __restrict__ csr) {
    __shared__ int offs[512];
    __shared__ int elds[BCAP];    // 38 KB
    int b = blockIdx.x;
    int nbase = b << SH;
    int base = rp[nbase];
    int lim = nbase + 512; if (lim > N_NODES) lim = N_NODES;
    int nedge = rp[lim] - base;
    if (nedge > BCAP) nedge = BCAP;
    for (int i = threadIdx.x; i < 512; i += 512) {
        int node = nbase + i;
        offs[i] = (node < N_NODES) ? (rp[node] - base) : nedge;
    }
    __syncthreads();
    int n = bcnt[b]; if (n > BCAP) n = BCAP;
    const unsigned int* pb = packed + (size_t)b * BCAP;
    for (int i = threadIdx.x; i < n; i += 512) {
        unsigned int p = pb[i];
        int pos = atomicAdd(&offs[p & 511u], 1);
        if (pos < BCAP) elds[pos] = (int)(p >> SH);
    }
    __syncthreads();
    for (int i = threadIdx.x; i < nedge; i += 512)
        csr[base + i] = elds[i];
}

// ---------------- MFMA GEMM: in[N,K] @ W[K,64] -> out slice-major bf16 --------
// out layout: [2 slices][N_NODES][32 feats] bf16: slice s is a contiguous
// 6.4 MB block; 64-B rows = one cache line per edge-slice gather request.
template <int K>
__global__ __launch_bounds__(256) void k_gemm(const void* __restrict__ x,
                                              const void* __restrict__ W,
                                              const float* __restrict__ dis,
                                              unsigned short* __restrict__ out,  // bf16 bits
                                              const int* __restrict__ flags,
                                              int x_is_f32, int in_sm) {
    int Wf32 = flags[0];
    int xF32 = (x_is_f32 < 0) ? Wf32 : x_is_f32;
    __shared__ unsigned short Wt[64][K + 8];
    __shared__ unsigned short xs[32][K + 8];
    int t = threadIdx.x;
    int wave = t >> 6, lane = t & 63;
    int quad = lane >> 4, l16 = lane & 15;

    for (int id = t; id < 64 * K; id += 256) {
        int k = id >> 6, n = id & 63;
        Wt[n][k] = f2bf(loadf(W, id, Wf32));
    }
    __syncthreads();

    bf16x8 bfrag[K / 32];
#pragma unroll
    for (int c = 0; c < K / 32; ++c)
        bfrag[c] = *reinterpret_cast<bf16x8*>(&Wt[wave * 16 + l16][c * 32 + quad * 8]);

    const int ngroups = (N_NODES + 31) / 32;
    for (int g = blockIdx.x; g < ngroups; g += gridDim.x) {
        __syncthreads();
        int row0 = g * 32;
        if (in_sm) {
            // slice-major input (K==64, [2][N][32]): per slice, 32 rows x 64 B
            // = 128 contiguous u32x4; 128 threads cover one slice.
            for (int cid = t; cid < 4 * K; cid += 256) {
                int slice = cid >> 7, i = cid & 127;
                int rr = i >> 2, qq = i & 3;
                int r = row0 + rr;
                u32x4 val = {0u, 0u, 0u, 0u};
                if (r < N_NODES)
                    val = ((const u32x4*)x)[((size_t)slice * N_NODES + row0) * 4 + i];
                *reinterpret_cast<u32x4*>(&xs[rr][slice * 32 + qq * 8]) = val;
            }
        } else {
            for (int cid = t; cid < 4 * K; cid += 256) {
                int rr = cid / (K / 8), c8 = cid % (K / 8);
                int r = row0 + rr;
                u32x4 val = {0u, 0u, 0u, 0u};
                if (r < N_NODES) {
                    size_t base = (size_t)r * K + c8 * 8;
                    if (xF32) {
                        const u32x4* xp = (const u32x4*)x;
                        u32x4 q0 = xp[base / 4];
                        u32x4 q1 = xp[base / 4 + 1];
                        val.x = f2bf(__uint_as_float(q0.x)) | ((unsigned int)f2bf(__uint_as_float(q0.y)) << 16);
                        val.y = f2bf(__uint_as_float(q0.z)) | ((unsigned int)f2bf(__uint_as_float(q0.w)) << 16);
                        val.z = f2bf(__uint_as_float(q1.x)) | ((unsigned int)f2bf(__uint_as_float(q1.y)) << 16);
                        val.w = f2bf(__uint_as_float(q1.z)) | ((unsigned int)f2bf(__uint_as_float(q1.w)) << 16);
                    } else {
                        val = ((const u32x4*)x)[base / 8];
                    }
                }
                *reinterpret_cast<u32x4*>(&xs[rr][c8 * 8]) = val;
            }
        }
        __syncthreads();

        f32x4 acc0 = {0.f, 0.f, 0.f, 0.f};
        f32x4 acc1 = {0.f, 0.f, 0.f, 0.f};
#pragma unroll
        for (int c = 0; c < K / 32; ++c) {
            bf16x8 a0 = *reinterpret_cast<bf16x8*>(&xs[l16][c * 32 + quad * 8]);
            bf16x8 a1 = *reinterpret_cast<bf16x8*>(&xs[16 + l16][c * 32 + quad * 8]);
            acc0 = __builtin_amdgcn_mfma_f32_16x16x32_bf16(a0, bfrag[c], acc0, 0, 0, 0);
            acc1 = __builtin_amdgcn_mfma_f32_16x16x32_bf16(a1, bfrag[c], acc1, 0, 0, 0);
        }
        // col = wave*16 + l16 -> slice = col>>5, within-slice feat = col&31
        int col = wave * 16 + l16;
        unsigned short* ow = out + (size_t)(col >> 5) * (N_NODES * 32);
        int f = col & 31;
#pragma unroll
        for (int reg = 0; reg < 4; ++reg) {
            int r0 = row0 + quad * 4 + reg;
            if (r0 < N_NODES) ow[(size_t)r0 * 32 + f] = f2bf(acc0[reg] * dis[r0]);
            int r1 = row0 + 16 + quad * 4 + reg;
            if (r1 < N_NODES) ow[(size_t)r1 * 32 + f] = f2bf(acc1[reg] * dis[r1]);
        }
    }
}

// ---------------- CSR gather: 4 concurrent node-packs per wave ----------------
// R7 post-mortem: duration fits time ~ requests x latency / in-flight; the ni
// loop ran its 4 packs sequentially with only ~2 loads in flight per wave.
// Now all 4 packs run CONCURRENTLY (separate accumulators a[4][8], separate
// csr prefetch streams) -> 8 independent loads in flight per wave, and the
// unified loop runs max-of-16 iterations instead of sum of 4 max-of-4 (~3x
// fewer). Unlike R5's failed 2-deep (same-acc chain, extra masking), VALU
// work is conserved and chains are independent. Lane map unchanged:
// lane = nodesub(4) x eslot(4) x quarter(4); 64-B rows; xcd affinity kept.
__global__ __launch_bounds__(256) void k_gather_sm(const int* __restrict__ rp,
                                                   const int* __restrict__ csr,
                                                   const float* __restrict__ dis,
                                                   const unsigned short* __restrict__ xws,
                                                   const void* __restrict__ bias,
                                                   unsigned short* __restrict__ out,
                                                   int do_relu,
                                                   const int* __restrict__ flags) {
    int F32 = flags[0];
    int blk = blockIdx.x;
    int xcd = blk & 7;
    int s = xcd >> 2;                              // slice 0..1
    int grp = ((blk >> 3) << 2) | (xcd & 3);       // 64-node group
    int wave = threadIdx.x >> 6, lane = threadIdx.x & 63;
    int nodesub = lane >> 4;                       // 0..3
    int eslot = (lane >> 2) & 3;                   // 0..3
    int q = lane & 3;                              // 0..3 (16-B quarter of 64-B row)
    const u32x4* xs4 = (const u32x4*)(xws + (size_t)s * N_NODES * 32);  // row = 4 u32x4
    u32x4* op = (u32x4*)out + (size_t)s * N_NODES * 4;
    // per-lane bias: 8 bf16 feats of this (slice, quarter)
    float bb0 = loadf(bias, s * 32 + q * 8 + 0, F32);
    float bb1 = loadf(bias, s * 32 + q * 8 + 1, F32);
    float bb2 = loadf(bias, s * 32 + q * 8 + 2, F32);
    float bb3 = loadf(bias, s * 32 + q * 8 + 3, F32);
    float bb4 = loadf(bias, s * 32 + q * 8 + 4, F32);
    float bb5 = loadf(bias, s * 32 + q * 8 + 5, F32);
    float bb6 = loadf(bias, s * 32 + q * 8 + 6, F32);
    float bb7 = loadf(bias, s * 32 + q * 8 + 7, F32);
    int wbase = grp * 64 + wave * 16;

    int jj[4], ee[4], ss[4], ok[4];
    float a[4][8];
#pragma unroll
    for (int p = 0; p < 4; ++p) {
        int node = wbase + p * 4 + nodesub;
        int valid = node < N_NODES;
        int st = valid ? rp[node] : 0;
        ee[p] = valid ? rp[node + 1] : 0;
        jj[p] = st + eslot;
        ok[p] = jj[p] < ee[p];
        ss[p] = ok[p] ? csr[jj[p]] : 0;
#pragma unroll
        for (int f = 0; f < 8; ++f) a[p][f] = 0.f;
    }

    while (ok[0] | ok[1] | ok[2] | ok[3]) {
        u32x4 v[4];
        int sn[4], okn[4];
        // phase 1: issue 4 independent row gathers
#pragma unroll
        for (int p = 0; p < 4; ++p)
            if (ok[p]) v[p] = xs4[(size_t)ss[p] * 4 + q];
        // phase 2: issue 4 independent next-index loads
#pragma unroll
        for (int p = 0; p < 4; ++p) {
            int jn = jj[p] + 4;
            okn[p] = ok[p] & (jn < ee[p]);
            sn[p] = 0;
            if (okn[p]) sn[p] = csr[jn];
            jj[p] = jn;
        }
        // phase 3: accumulate
#pragma unroll
        for (int p = 0; p < 4; ++p) {
            if (ok[p]) {
                a[p][0] += bf2f(v[p].x & 0xFFFFu); a[p][1] += bf2f(v[p].x >> 16);
                a[p][2] += bf2f(v[p].y & 0xFFFFu); a[p][3] += bf2f(v[p].y >> 16);
                a[p][4] += bf2f(v[p].z & 0xFFFFu); a[p][5] += bf2f(v[p].z >> 16);
                a[p][6] += bf2f(v[p].w & 0xFFFFu); a[p][7] += bf2f(v[p].w >> 16);
            }
            ok[p] = okn[p];
            ss[p] = sn[p];
        }
    }

    // reduce over eslot (lane bits 2-3: offsets 4, 8), per pack
#pragma unroll
    for (int p = 0; p < 4; ++p) {
#pragma unroll
        for (int off = 4; off <= 8; off <<= 1) {
            a[p][0] += __shfl_down(a[p][0], off, 64); a[p][1] += __shfl_down(a[p][1], off, 64);
            a[p][2] += __shfl_down(a[p][2], off, 64); a[p][3] += __shfl_down(a[p][3], off, 64);
            a[p][4] += __shfl_down(a[p][4], off, 64); a[p][5] += __shfl_down(a[p][5], off, 64);
            a[p][6] += __shfl_down(a[p][6], off, 64); a[p][7] += __shfl_down(a[p][7], off, 64);
        }
    }

    if ((lane & 12) == 0) {   // eslot == 0: 16 lanes (4 nodes x 4 quarters)
#pragma unroll
        for (int p = 0; p < 4; ++p) {
            int node = wbase + p * 4 + nodesub;
            if (node < N_NODES) {
                u32x4 sv = xs4[(size_t)node * 4 + q];   // self row (cache-hot)
                float dn = dis[node];
                float v0 = fmaf(a[p][0] + bf2f(sv.x & 0xFFFFu), dn, bb0);
                float v1 = fmaf(a[p][1] + bf2f(sv.x >> 16),     dn, bb1);
                float v2 = fmaf(a[p][2] + bf2f(sv.y & 0xFFFFu), dn, bb2);
                float v3 = fmaf(a[p][3] + bf2f(sv.y >> 16),     dn, bb3);
                float v4 = fmaf(a[p][4] + bf2f(sv.z & 0xFFFFu), dn, bb4);
                float v5 = fmaf(a[p][5] + bf2f(sv.z >> 16),     dn, bb5);
                float v6 = fmaf(a[p][6] + bf2f(sv.w & 0xFFFFu), dn, bb6);
                float v7 = fmaf(a[p][7] + bf2f(sv.w >> 16),     dn, bb7);
                if (do_relu) {
                    v0 = fmaxf(v0, 0.f); v1 = fmaxf(v1, 0.f); v2 = fmaxf(v2, 0.f); v3 = fmaxf(v3, 0.f);
                    v4 = fmaxf(v4, 0.f); v5 = fmaxf(v5, 0.f); v6 = fmaxf(v6, 0.f); v7 = fmaxf(v7, 0.f);
                }
                u32x4 o;
                o.x = (unsigned int)f2bf(v0) | ((unsigned int)f2bf(v1) << 16);
                o.y = (unsigned int)f2bf(v2) | ((unsigned int)f2bf(v3) << 16);
                o.z = (unsigned int)f2bf(v4) | ((unsigned int)f2bf(v5) << 16);
                o.w = (unsigned int)f2bf(v6) | ((unsigned int)f2bf(v7) << 16);
                op[(size_t)node * 4 + q] = o;
            }
        }
    }
}

// ---------------- fused mean-pool + linear head (1 graph/block) ---------------
// [2][N][32] layout: 4 waves = 2 slices x 2 node-parity groups; lane =
// nodesub(4) x u32feat(16): each wave-instr reads 4 nodes x 64 B contiguous.
__global__ __launch_bounds__(256) void k_pool_final(const int* __restrict__ gptr,
                             const unsigned short* __restrict__ h,   // slice-major
                             const void* __restrict__ Wl, const void* __restrict__ bl,
                             void* __restrict__ out, const int* __restrict__ flags) {
    int F32 = flags[0];
    __shared__ float part[4];
    int g = blockIdx.x;
    int w = threadIdx.x >> 6;
    int s = w >> 1;                  // slice 0..1
    int wo = w & 1;                  // node parity group
    int lane = threadIdx.x & 63;
    int nsub = lane >> 4, up = lane & 15;
    int s0 = gptr[g], e0 = gptr[g + 1];
    const unsigned int* xsl = (const unsigned int*)h + (size_t)s * N_NODES * 16;
    float a0 = 0.f, a1 = 0.f;
    for (int n = s0 + wo * 4 + nsub; n < e0; n += 8) {
        unsigned int v = xsl[(size_t)n * 16 + up];
        a0 += bf2f(v & 0xFFFFu);
        a1 += bf2f(v >> 16);
    }
    a0 += __shfl_down(a0, 32, 64); a1 += __shfl_down(a1, 32, 64);
    a0 += __shfl_down(a0, 16, 64); a1 += __shfl_down(a1, 16, 64);
    float v = 0.f;
    if (nsub == 0) {
        float cnt = fmaxf((float)(e0 - s0), 1.0f);
        int f = s * 32 + up * 2;
        v = (a0 / cnt) * loadf(Wl, f, F32) + (a1 / cnt) * loadf(Wl, f + 1, F32);
    }
    v += __shfl_down(v, 8, 64);
    v += __shfl_down(v, 4, 64);
    v += __shfl_down(v, 2, 64);
    v += __shfl_down(v, 1, 64);
    if (lane == 0) part[w] = v;
    __syncthreads();
    if (threadIdx.x == 0) {
        float r = part[0] + part[1] + part[2] + part[3] + loadf(bl, 0, F32);
        if (F32) ((float*)out)[g] = r;
        else     ((__hip_bfloat16*)out)[g] = __float2bfloat16(r);
    }
}

extern "C" void kernel_launch(void* const* d_in, const int* in_sizes, int n_in,
                              void* d_out, int out_size, void* d_ws, size_t ws_size,
                              hipStream_t stream) {
    const void* x     = d_in[0];
    const void* ei    = d_in[1];
    const void* batch = d_in[2];
    const void* W1 = d_in[3];
    const void* b1 = d_in[4];
    const void* W2 = d_in[5];
    const void* b2 = d_in[6];
    const void* W3 = d_in[7];
    const void* b3 = d_in[8];
    const void* Wl = d_in[9];
    const void* bl = d_in[10];

    // workspace layout (~41 MB)
    float* dis   = (float*)d_ws;             // 100352
    int*   cnt   = (int*)(dis + 100352);     // 100352
    int*   rp    = cnt + 100352;             // 100352 (needs 100001)
    int*   csr   = rp + 100352;              // 1600000
    int*   gcnt  = csr + 1600000;            // 1024
    int*   gptr  = gcnt + 1024;              // 1056 (needs 1025)
    int*   partN = gptr + 1056;              // 512
    int*   bcnt  = partN + 512;              // 256
    int*   flags = bcnt + 256;               // 16
    unsigned int* packed = (unsigned int*)(flags + 16);    // NB*BCAP (7.8 MB)
    unsigned short* bufA = (unsigned short*)(packed + (size_t)NB * BCAP);  // bf16 slice-major (12.8 MB)
    unsigned short* bufB = bufA + (size_t)NSLICE * N_NODES * 32;           // bf16 slice-major (12.8 MB)

    const int TB = 256;
    dim3 blk(TB);
    int gN = (N_NODES + TB - 1) / TB;        // 391
    // gather grid: 391 group-quads x 8 xcd-slots -> grp 0..1563 covers 100096 nodes
    int gGA = 391 * 8;

    // init: detect + zero small counters
    k_init<<<1, blk, 0, stream>>>((const unsigned int*)x, (const unsigned int*)ei,
                                  flags, gcnt, bcnt);
    // phase A partition (two-pass fat blocks with LDS staging, + batch counts)
    k_part<<<(N_EDGES + EPB - 1) / EPB, blk, 0, stream>>>(ei, batch, bcnt, gcnt, packed, flags);
    // hist: cnt + dis + scan partials
    k_hist<<<NBU, blk, 0, stream>>>(packed, bcnt, cnt, dis, partN);
    // middle scan: partN exclusive + rp[N] + graph scan -> gptr
    k_scan_mid<<<1, 512, 0, stream>>>(partN, gN, rp, N_NODES, gcnt, gptr);
    // p3: rp
    k_scan_p3<<<gN, blk, 0, stream>>>(cnt, partN, rp, N_NODES);
    // phase B: dense csr (sorted by dst)
    k_bucketcsr<<<NBU, 512, 0, stream>>>(packed, bcnt, rp, csr);

    // ---- layer 1 ----
    k_gemm<F_IN><<<1024, blk, 0, stream>>>(x, W1, dis, bufA, flags, -1, 0);
    k_gather_sm<<<gGA, blk, 0, stream>>>(rp, csr, dis, bufA, b1, bufB, 1, flags);
    // ---- layer 2 ----
    k_gemm<HID><<<1024, blk, 0, stream>>>(bufB, W2, dis, bufA, flags, 0, 1);
    k_gather_sm<<<gGA, blk, 0, stream>>>(rp, csr, dis, bufA, b2, bufB, 1, flags);
    // ---- layer 3 ----
    k_gemm<HID><<<1024, blk, 0, stream>>>(bufB, W3, dis, bufA, flags, 0, 1);
    k_gather_sm<<<gGA, blk, 0, stream>>>(rp, csr, dis, bufA, b3, bufB, 0, flags);

    // ---- pool + head ----
    k_pool_final<<<N_GRAPHS, blk, 0, stream>>>(gptr, bufB, Wl, bl, d_out, flags);
}

// Round 9
// 338.509 us; speedup vs baseline: 1.1848x; 1.1848x over previous
//
#include <hip/hip_runtime.h>
#include <hip/hip_bf16.h>

#define N_NODES 100000
#define N_EDGES 1600000
#define F_IN 128
#define HID 64
#define N_GRAPHS 1024

// fine dst-partition: bucket = dst>>9 (512 nodes/bucket)
#define SH 9
#define NBU 196        // buckets used: ceil(100000/512)
#define NB 200         // allocated
#define BCAP 9728      // mean 8192 + 17 sigma
#define EPB 2048       // R8: edges per k_part block (782 blocks, ~3/CU; was 196 fat blocks = 0.77/CU)
#define NSLICE 2       // 2 slices x 32 feats (64-B rows): one cache line per edge-slice request

typedef __attribute__((ext_vector_type(8))) short bf16x8;
typedef __attribute__((ext_vector_type(4))) float f32x4;
typedef __attribute__((ext_vector_type(4))) unsigned int u32x4;

// ---------------- bf16 bit helpers --------------------------------------------
__device__ __forceinline__ unsigned short f2bf(float f) {
    __hip_bfloat16 h = __float2bfloat16(f);   // RNE
    return *reinterpret_cast<unsigned short*>(&h);
}
__device__ __forceinline__ float bf2f(unsigned int u) {
    return __uint_as_float(u << 16);
}

// ---------------- dual-path load helpers (wire dtype resolved at runtime) -----
__device__ __forceinline__ float loadf(const void* p, size_t i, int f32) {
    if (f32) return ((const float*)p)[i];
    return __bfloat162float(((const __hip_bfloat16*)p)[i]);
}
__device__ __forceinline__ int loadi(const void* p, size_t i, int i64) {
    if (i64) return (int)((const long long*)p)[i];
    return ((const int*)p)[i];
}

// ---------------- init: wire detect + zero small counters ---------------------
__global__ void k_init(const unsigned int* __restrict__ xw_,
                       const unsigned int* __restrict__ ei_,
                       int* __restrict__ flags,
                       int* __restrict__ gcnt, int* __restrict__ bcnt) {
    __shared__ int cnt_f, cnt_i;
    int t = threadIdx.x;
    if (t == 0) { cnt_f = 0; cnt_i = 0; }
    __syncthreads();
    unsigned int w = xw_[t];
    unsigned int e = (w >> 7) & 0xFFu;
    if (e >= 100u && e <= 140u) atomicAdd(&cnt_f, 1);
    unsigned int iw = ei_[2 * t + 1];
    if (iw == 0u) atomicAdd(&cnt_i, 1);
    for (int i = t; i < N_GRAPHS; i += 256) gcnt[i] = 0;
    for (int i = t; i < NB; i += 256) bcnt[i] = 0;
    __syncthreads();
    if (t == 0) {
        flags[0] = (cnt_f < 180) ? 1 : 0;   // 1 => fp32 wire
        flags[1] = (cnt_i >= 128) ? 1 : 0;  // 1 => int64 wire
    }
}

// ---------------- phase A: partition by dst>>9, two-pass blocks ---------------
// LDS-staged decode (R4). R8: 782 slim blocks (EPB=2048) instead of 196 fat
// ones -> ~3 blocks/CU for this memory-streaming kernel. Batch counting:
// block covers nodes [blk*128, blk*128+128).
__global__ __launch_bounds__(256) void k_part(const void* __restrict__ ei,
                                              const void* __restrict__ batch,
                                              int* __restrict__ bcnt,
                                              int* __restrict__ gcnt,
                                              unsigned int* __restrict__ packed,
                                              const int* __restrict__ flags) {
    int I64 = flags[1];
    __shared__ int hist[NB];
    __shared__ int base[NB];
    __shared__ int ghist[N_GRAPHS];        // 4 KB
    __shared__ unsigned int elds[EPB];     // 8 KB: packed words
    __shared__ unsigned char ebkt[EPB];    // 2 KB: bucket ids (0xFF = invalid)
    int t = threadIdx.x;
    if (t < NB) hist[t] = 0;
    for (int i = t; i < N_GRAPHS; i += 256) ghist[i] = 0;
    __syncthreads();
    // batch counting: block covers nodes [blk*128, blk*128+128)
    if (t < 128) {
        int n = blockIdx.x * 128 + t;
        if (n < N_NODES) atomicAdd(&ghist[loadi(batch, n, I64)], 1);
    }
    // edge pass 1: decode once, stage in LDS, bucket counts
    int e0 = blockIdx.x * EPB;
#pragma unroll 4
    for (int it = 0; it < EPB / 256; ++it) {
        int idx = it * 256 + t;
        int e = e0 + idx;
        unsigned int pv = 0u;
        unsigned char bk = 0xFFu;
        if (e < N_EDGES) {
            int sN = loadi(ei, e, I64);
            int d = loadi(ei, (size_t)N_EDGES + e, I64);
            bk = (unsigned char)(d >> SH);
            pv = ((unsigned int)sN << SH) | (unsigned int)(d & 511);
            atomicAdd(&hist[d >> SH], 1);
        }
        elds[idx] = pv;
        ebkt[idx] = bk;
    }
    __syncthreads();
    if (t < NB) {
        base[t] = hist[t] ? atomicAdd(&bcnt[t], hist[t]) : 0;
        hist[t] = 0;   // reuse as pass-2 rank counter
    }
    for (int i = t; i < N_GRAPHS; i += 256)
        if (ghist[i]) atomicAdd(&gcnt[i], ghist[i]);
    __syncthreads();
    // edge pass 2: rank + write from LDS
#pragma unroll 4
    for (int it = 0; it < EPB / 256; ++it) {
        int idx = it * 256 + t;
        unsigned char bk = ebkt[idx];
        if (bk != 0xFFu) {
            unsigned int pv = elds[idx];
            int r = atomicAdd(&hist[bk], 1);
            int pos = base[bk] + r;
            if (pos < BCAP)
                packed[(size_t)bk * BCAP + pos] = pv;
        }
    }
}

// ---------------- fused CSR build: hist + local scan + sort + dis + rp2 -------
// R8: csr is PER-BUCKET dense at b*BCAP (nothing needs global density), so the
// node offsets come from a bucket-local 512-entry LDS scan. This one kernel
// replaces k_hist + partN-scan + k_scan_p3 + k_bucketcsr. rp2[node] =
// (start, end) absolute into the padded csr array -> gather loads one int2.
__global__ __launch_bounds__(512) void k_csr(const unsigned int* __restrict__ packed,
                                             const int* __restrict__ bcnt,
                                             float* __restrict__ dis,
                                             int2* __restrict__ rp2,
                                             int* __restrict__ csr) {
    __shared__ int hist[512];
    __shared__ int offs[512];
    __shared__ int elds[BCAP];    // 38 KB
    int b = blockIdx.x;
    int t = threadIdx.x;
    int n = bcnt[b]; if (n > BCAP) n = BCAP;
    hist[t] = 0;
    __syncthreads();
    const unsigned int* pb = packed + (size_t)b * BCAP;
    for (int i = t; i < n; i += 512)
        atomicAdd(&hist[pb[i] & 511u], 1);
    __syncthreads();
    // inclusive scan of counts -> offs, then exclusive = offs - c
    int c = hist[t];
    offs[t] = c;
    __syncthreads();
    for (int off = 1; off < 512; off <<= 1) {
        int x = (t >= off) ? offs[t - off] : 0;
        __syncthreads();
        offs[t] += x;
        __syncthreads();
    }
    int excl = offs[t] - c;
    int node = (b << SH) + t;
    int base = b * BCAP;
    if (node < N_NODES) {
        dis[node] = rsqrtf((float)c + 1.0f);
        rp2[node] = make_int2(base + excl, base + excl + c);
    }
    __syncthreads();
    offs[t] = excl;               // running scatter counters
    __syncthreads();
    for (int i = t; i < n; i += 512) {
        unsigned int p = pb[i];
        int pos = atomicAdd(&offs[p & 511u], 1);
        if (pos < BCAP) elds[pos] = (int)(p >> SH);
    }
    __syncthreads();
    for (int i = t; i < n; i += 512)
        csr[base + i] = elds[i];
}

// ---------------- graph scan: gcnt (1024) -> gptr, one block ------------------
__global__ void k_gscan(const int* __restrict__ gcnt, int* __restrict__ gptr) {
    __shared__ int s[512];
    int t = threadIdx.x;
    int a = gcnt[2 * t], bq = gcnt[2 * t + 1];
    int ps = a + bq;
    s[t] = ps;
    __syncthreads();
    for (int off = 1; off < 512; off <<= 1) {
        int x = (t >= off) ? s[t - off] : 0;
        __syncthreads();
        s[t] += x;
        __syncthreads();
    }
    int excl = s[t] - ps;
    gptr[2 * t] = excl;
    gptr[2 * t + 1] = excl + a;
    if (t == 511) gptr[1024] = s[511];
}

// ---------------- MFMA GEMM: in[N,K] @ W[K,64] -> out slice-major bf16 --------
// out layout: [2 slices][N_NODES][32 feats] bf16: slice s is a contiguous
// 6.4 MB block; 64-B rows = one cache line per edge-slice gather request.
template <int K>
__global__ __launch_bounds__(256) void k_gemm(const void* __restrict__ x,
                                              const void* __restrict__ W,
                                              const float* __restrict__ dis,
                                              unsigned short* __restrict__ out,  // bf16 bits
                                              const int* __restrict__ flags,
                                              int x_is_f32, int in_sm) {
    int Wf32 = flags[0];
    int xF32 = (x_is_f32 < 0) ? Wf32 : x_is_f32;
    __shared__ unsigned short Wt[64][K + 8];
    __shared__ unsigned short xs[32][K + 8];
    int t = threadIdx.x;
    int wave = t >> 6, lane = t & 63;
    int quad = lane >> 4, l16 = lane & 15;

    for (int id = t; id < 64 * K; id += 256) {
        int k = id >> 6, n = id & 63;
        Wt[n][k] = f2bf(loadf(W, id, Wf32));
    }
    __syncthreads();

    bf16x8 bfrag[K / 32];
#pragma unroll
    for (int c = 0; c < K / 32; ++c)
        bfrag[c] = *reinterpret_cast<bf16x8*>(&Wt[wave * 16 + l16][c * 32 + quad * 8]);

    const int ngroups = (N_NODES + 31) / 32;
    for (int g = blockIdx.x; g < ngroups; g += gridDim.x) {
        __syncthreads();
        int row0 = g * 32;
        if (in_sm) {
            // slice-major input (K==64, [2][N][32]): per slice, 32 rows x 64 B
            // = 128 contiguous u32x4; 128 threads cover one slice.
            for (int cid = t; cid < 4 * K; cid += 256) {
                int slice = cid >> 7, i = cid & 127;
                int rr = i >> 2, qq = i & 3;
                int r = row0 + rr;
                u32x4 val = {0u, 0u, 0u, 0u};
                if (r < N_NODES)
                    val = ((const u32x4*)x)[((size_t)slice * N_NODES + row0) * 4 + i];
                *reinterpret_cast<u32x4*>(&xs[rr][slice * 32 + qq * 8]) = val;
            }
        } else {
            for (int cid = t; cid < 4 * K; cid += 256) {
                int rr = cid / (K / 8), c8 = cid % (K / 8);
                int r = row0 + rr;
                u32x4 val = {0u, 0u, 0u, 0u};
                if (r < N_NODES) {
                    size_t base = (size_t)r * K + c8 * 8;
                    if (xF32) {
                        const u32x4* xp = (const u32x4*)x;
                        u32x4 q0 = xp[base / 4];
                        u32x4 q1 = xp[base / 4 + 1];
                        val.x = f2bf(__uint_as_float(q0.x)) | ((unsigned int)f2bf(__uint_as_float(q0.y)) << 16);
                        val.y = f2bf(__uint_as_float(q0.z)) | ((unsigned int)f2bf(__uint_as_float(q0.w)) << 16);
                        val.z = f2bf(__uint_as_float(q1.x)) | ((unsigned int)f2bf(__uint_as_float(q1.y)) << 16);
                        val.w = f2bf(__uint_as_float(q1.z)) | ((unsigned int)f2bf(__uint_as_float(q1.w)) << 16);
                    } else {
                        val = ((const u32x4*)x)[base / 8];
                    }
                }
                *reinterpret_cast<u32x4*>(&xs[rr][c8 * 8]) = val;
            }
        }
        __syncthreads();

        f32x4 acc0 = {0.f, 0.f, 0.f, 0.f};
        f32x4 acc1 = {0.f, 0.f, 0.f, 0.f};
#pragma unroll
        for (int c = 0; c < K / 32; ++c) {
            bf16x8 a0 = *reinterpret_cast<bf16x8*>(&xs[l16][c * 32 + quad * 8]);
            bf16x8 a1 = *reinterpret_cast<bf16x8*>(&xs[16 + l16][c * 32 + quad * 8]);
            acc0 = __builtin_amdgcn_mfma_f32_16x16x32_bf16(a0, bfrag[c], acc0, 0, 0, 0);
            acc1 = __builtin_amdgcn_mfma_f32_16x16x32_bf16(a1, bfrag[c], acc1, 0, 0, 0);
        }
        // col = wave*16 + l16 -> slice = col>>5, within-slice feat = col&31
        int col = wave * 16 + l16;
        unsigned short* ow = out + (size_t)(col >> 5) * (N_NODES * 32);
        int f = col & 31;
#pragma unroll
        for (int reg = 0; reg < 4; ++reg) {
            int r0 = row0 + quad * 4 + reg;
            if (r0 < N_NODES) ow[(size_t)r0 * 32 + f] = f2bf(acc0[reg] * dis[r0]);
            int r1 = row0 + 16 + quad * 4 + reg;
            if (r1 < N_NODES) ow[(size_t)r1 * 32 + f] = f2bf(acc1[reg] * dis[r1]);
        }
    }
}

// ---------------- CSR shuffle-reduce gather, 64-B rows (R7 revert) ------------
// R8 post-mortem: concurrent-pack while-loop regressed (occupancy 56->31%,
// sum->max trip inflation, branchy conditional loads) -> exact R7 structure:
// sequential ni packs, single-stream prefetch. Only change: rp2 int2 load.
// lane = nodesub(4) x eslot(4) x quarter(4); xcd = blk&7, slice = xcd>>2.
__global__ __launch_bounds__(256) void k_gather_sm(const int2* __restrict__ rp2,
                                                   const int* __restrict__ csr,
                                                   const float* __restrict__ dis,
                                                   const unsigned short* __restrict__ xws,
                                                   const void* __restrict__ bias,
                                                   unsigned short* __restrict__ out,
                                                   int do_relu,
                                                   const int* __restrict__ flags) {
    int F32 = flags[0];
    int blk = blockIdx.x;
    int xcd = blk & 7;
    int s = xcd >> 2;                              // slice 0..1
    int grp = ((blk >> 3) << 2) | (xcd & 3);       // 64-node group
    int wave = threadIdx.x >> 6, lane = threadIdx.x & 63;
    int nodesub = lane >> 4;                       // 0..3
    int eslot = (lane >> 2) & 3;                   // 0..3
    int q = lane & 3;                              // 0..3 (16-B quarter of 64-B row)
    const u32x4* xs4 = (const u32x4*)(xws + (size_t)s * N_NODES * 32);  // row = 4 u32x4
    u32x4* op = (u32x4*)out + (size_t)s * N_NODES * 4;
    // per-lane bias: 8 bf16 feats of this (slice, quarter)
    float bb0 = loadf(bias, s * 32 + q * 8 + 0, F32);
    float bb1 = loadf(bias, s * 32 + q * 8 + 1, F32);
    float bb2 = loadf(bias, s * 32 + q * 8 + 2, F32);
    float bb3 = loadf(bias, s * 32 + q * 8 + 3, F32);
    float bb4 = loadf(bias, s * 32 + q * 8 + 4, F32);
    float bb5 = loadf(bias, s * 32 + q * 8 + 5, F32);
    float bb6 = loadf(bias, s * 32 + q * 8 + 6, F32);
    float bb7 = loadf(bias, s * 32 + q * 8 + 7, F32);
    int wbase = grp * 64 + wave * 16;

    for (int ni = 0; ni < 4; ++ni) {
        int node = wbase + ni * 4 + nodesub;
        int valid = node < N_NODES;
        int2 se = valid ? rp2[node] : make_int2(0, 0);
        int start = se.x, end = se.y;
        float a0 = 0.f, a1 = 0.f, a2 = 0.f, a3 = 0.f;
        float a4 = 0.f, a5 = 0.f, a6 = 0.f, a7 = 0.f;
        int j = start + eslot;
        if (j < end) {
            int src = csr[j];
            for (;;) {
                int jn = j + 4;
                int sn = (jn < end) ? csr[jn] : 0;   // prefetch next index
                u32x4 v = xs4[(size_t)src * 4 + q];
                a0 += bf2f(v.x & 0xFFFFu); a1 += bf2f(v.x >> 16);
                a2 += bf2f(v.y & 0xFFFFu); a3 += bf2f(v.y >> 16);
                a4 += bf2f(v.z & 0xFFFFu); a5 += bf2f(v.z >> 16);
                a6 += bf2f(v.w & 0xFFFFu); a7 += bf2f(v.w >> 16);
                if (jn >= end) break;
                j = jn; src = sn;
            }
        }
        // reduce over eslot (lane bits 2-3: offsets 4, 8)
#pragma unroll
        for (int off = 4; off <= 8; off <<= 1) {
            a0 += __shfl_down(a0, off, 64); a1 += __shfl_down(a1, off, 64);
            a2 += __shfl_down(a2, off, 64); a3 += __shfl_down(a3, off, 64);
            a4 += __shfl_down(a4, off, 64); a5 += __shfl_down(a5, off, 64);
            a6 += __shfl_down(a6, off, 64); a7 += __shfl_down(a7, off, 64);
        }
        if (((lane & 12) == 0) && valid) {   // eslot == 0: 16 lanes (4 nodes x 4 quarters)
            u32x4 sv = xs4[(size_t)node * 4 + q];   // self row (cache-hot)
            float dn = dis[node];
            float v0 = fmaf(a0 + bf2f(sv.x & 0xFFFFu), dn, bb0);
            float v1 = fmaf(a1 + bf2f(sv.x >> 16),     dn, bb1);
            float v2 = fmaf(a2 + bf2f(sv.y & 0xFFFFu), dn, bb2);
            float v3 = fmaf(a3 + bf2f(sv.y >> 16),     dn, bb3);
            float v4 = fmaf(a4 + bf2f(sv.z & 0xFFFFu), dn, bb4);
            float v5 = fmaf(a5 + bf2f(sv.z >> 16),     dn, bb5);
            float v6 = fmaf(a6 + bf2f(sv.w & 0xFFFFu), dn, bb6);
            float v7 = fmaf(a7 + bf2f(sv.w >> 16),     dn, bb7);
            if (do_relu) {
                v0 = fmaxf(v0, 0.f); v1 = fmaxf(v1, 0.f); v2 = fmaxf(v2, 0.f); v3 = fmaxf(v3, 0.f);
                v4 = fmaxf(v4, 0.f); v5 = fmaxf(v5, 0.f); v6 = fmaxf(v6, 0.f); v7 = fmaxf(v7, 0.f);
            }
            u32x4 o;
            o.x = (unsigned int)f2bf(v0) | ((unsigned int)f2bf(v1) << 16);
            o.y = (unsigned int)f2bf(v2) | ((unsigned int)f2bf(v3) << 16);
            o.z = (unsigned int)f2bf(v4) | ((unsigned int)f2bf(v5) << 16);
            o.w = (unsigned int)f2bf(v6) | ((unsigned int)f2bf(v7) << 16);
            op[(size_t)node * 4 + q] = o;
        }
    }
}

// ---------------- fused mean-pool + linear head (1 graph/block) ---------------
// [2][N][32] layout: 4 waves = 2 slices x 2 node-parity groups; lane =
// nodesub(4) x u32feat(16): each wave-instr reads 4 nodes x 64 B contiguous.
__global__ __launch_bounds__(256) void k_pool_final(const int* __restrict__ gptr,
                             const unsigned short* __restrict__ h,   // slice-major
                             const void* __restrict__ Wl, const void* __restrict__ bl,
                             void* __restrict__ out, const int* __restrict__ flags) {
    int F32 = flags[0];
    __shared__ float part[4];
    int g = blockIdx.x;
    int w = threadIdx.x >> 6;
    int s = w >> 1;                  // slice 0..1
    int wo = w & 1;                  // node parity group
    int lane = threadIdx.x & 63;
    int nsub = lane >> 4, up = lane & 15;
    int s0 = gptr[g], e0 = gptr[g + 1];
    const unsigned int* xsl = (const unsigned int*)h + (size_t)s * N_NODES * 16;
    float a0 = 0.f, a1 = 0.f;
    for (int n = s0 + wo * 4 + nsub; n < e0; n += 8) {
        unsigned int v = xsl[(size_t)n * 16 + up];
        a0 += bf2f(v & 0xFFFFu);
        a1 += bf2f(v >> 16);
    }
    a0 += __shfl_down(a0, 32, 64); a1 += __shfl_down(a1, 32, 64);
    a0 += __shfl_down(a0, 16, 64); a1 += __shfl_down(a1, 16, 64);
    float v = 0.f;
    if (nsub == 0) {
        float cnt = fmaxf((float)(e0 - s0), 1.0f);
        int f = s * 32 + up * 2;
        v = (a0 / cnt) * loadf(Wl, f, F32) + (a1 / cnt) * loadf(Wl, f + 1, F32);
    }
    v += __shfl_down(v, 8, 64);
    v += __shfl_down(v, 4, 64);
    v += __shfl_down(v, 2, 64);
    v += __shfl_down(v, 1, 64);
    if (lane == 0) part[w] = v;
    __syncthreads();
    if (threadIdx.x == 0) {
        float r = part[0] + part[1] + part[2] + part[3] + loadf(bl, 0, F32);
        if (F32) ((float*)out)[g] = r;
        else     ((__hip_bfloat16*)out)[g] = __float2bfloat16(r);
    }
}

extern "C" void kernel_launch(void* const* d_in, const int* in_sizes, int n_in,
                              void* d_out, int out_size, void* d_ws, size_t ws_size,
                              hipStream_t stream) {
    const void* x     = d_in[0];
    const void* ei    = d_in[1];
    const void* batch = d_in[2];
    const void* W1 = d_in[3];
    const void* b1 = d_in[4];
    const void* W2 = d_in[5];
    const void* b2 = d_in[6];
    const void* W3 = d_in[7];
    const void* b3 = d_in[8];
    const void* Wl = d_in[9];
    const void* bl = d_in[10];

    // workspace layout (~42 MB)
    float* dis   = (float*)d_ws;             // 100352
    int2*  rp2   = (int2*)(dis + 100352);    // 100352 int2 (start,end)
    int*   csr   = (int*)(rp2 + 100352);     // NB*BCAP (per-bucket dense, 7.8 MB)
    int*   gcnt  = csr + NB * BCAP;          // 1024
    int*   gptr  = gcnt + 1024;              // 1056 (needs 1025)
    int*   bcnt  = gptr + 1056;              // 256
    int*   flags = bcnt + 256;               // 16
    unsigned int* packed = (unsigned int*)(flags + 16);    // NB*BCAP (7.8 MB)
    unsigned short* bufA = (unsigned short*)(packed + (size_t)NB * BCAP);  // bf16 slice-major (12.8 MB)
    unsigned short* bufB = bufA + (size_t)NSLICE * N_NODES * 32;           // bf16 slice-major (12.8 MB)

    const int TB = 256;
    dim3 blk(TB);
    // gather grid: 391 group-quads x 8 xcd-slots -> grp 0..1563 covers 100096 nodes
    int gGA = 391 * 8;

    // init: detect + zero small counters
    k_init<<<1, blk, 0, stream>>>((const unsigned int*)x, (const unsigned int*)ei,
                                  flags, gcnt, bcnt);
    // phase A partition (782 slim blocks, LDS staging, + batch counts)
    k_part<<<(N_EDGES + EPB - 1) / EPB, blk, 0, stream>>>(ei, batch, bcnt, gcnt, packed, flags);
    // fused CSR build: hist + local scan + sort + dis + rp2
    k_csr<<<NBU, 512, 0, stream>>>(packed, bcnt, dis, rp2, csr);
    // graph scan -> gptr
    k_gscan<<<1, 512, 0, stream>>>(gcnt, gptr);

    // ---- layer 1 ----
    k_gemm<F_IN><<<1024, blk, 0, stream>>>(x, W1, dis, bufA, flags, -1, 0);
    k_gather_sm<<<gGA, blk, 0, stream>>>(rp2, csr, dis, bufA, b1, bufB, 1, flags);
    // ---- layer 2 ----
    k_gemm<HID><<<1024, blk, 0, stream>>>(bufB, W2, dis, bufA, flags, 0, 1);
    k_gather_sm<<<gGA, blk, 0, stream>>>(rp2, csr, dis, bufA, b2, bufB, 1, flags);
    // ---- layer 3 ----
    k_gemm<HID><<<1024, blk, 0, stream>>>(bufB, W3, dis, bufA, flags, 0, 1);
    k_gather_sm<<<gGA, blk, 0, stream>>>(rp2, csr, dis, bufA, b3, bufB, 0, flags);

    // ---- pool + head ----
    k_pool_final<<<N_GRAPHS, blk, 0, stream>>>(gptr, bufB, Wl, bl, d_out, flags);
}

// Round 10
// 331.679 us; speedup vs baseline: 1.2092x; 1.0206x over previous
//
#include <hip/hip_runtime.h>
#include <hip/hip_bf16.h>

#define N_NODES 100000
#define N_EDGES 1600000
#define F_IN 128
#define HID 64
#define N_GRAPHS 1024

// fine dst-partition: bucket = dst>>9 (512 nodes/bucket)
#define SH 9
#define NBU 196        // buckets used: ceil(100000/512)
#define NB 200         // allocated
#define BCAP 9728      // mean 8192 + 17 sigma
#define EPB 2048       // edges per k_part block (782 blocks, ~3/CU)
#define NSLICE 2       // gemm1 output: 2 slices x 32 feats (64-B rows)

typedef __attribute__((ext_vector_type(8))) short bf16x8;
typedef __attribute__((ext_vector_type(4))) float f32x4;
typedef __attribute__((ext_vector_type(4))) unsigned int u32x4;

// ---------------- bf16 bit helpers --------------------------------------------
__device__ __forceinline__ unsigned short f2bf(float f) {
    __hip_bfloat16 h = __float2bfloat16(f);   // RNE
    return *reinterpret_cast<unsigned short*>(&h);
}
__device__ __forceinline__ float bf2f(unsigned int u) {
    return __uint_as_float(u << 16);
}

// ---------------- dual-path load helpers (wire dtype resolved at runtime) -----
__device__ __forceinline__ float loadf(const void* p, size_t i, int f32) {
    if (f32) return ((const float*)p)[i];
    return __bfloat162float(((const __hip_bfloat16*)p)[i]);
}
__device__ __forceinline__ int loadi(const void* p, size_t i, int i64) {
    if (i64) return (int)((const long long*)p)[i];
    return ((const int*)p)[i];
}

// ---------------- init: wire detect + zero small counters ---------------------
__global__ void k_init(const unsigned int* __restrict__ xw_,
                       const unsigned int* __restrict__ ei_,
                       int* __restrict__ flags,
                       int* __restrict__ gcnt, int* __restrict__ bcnt) {
    __shared__ int cnt_f, cnt_i;
    int t = threadIdx.x;
    if (t == 0) { cnt_f = 0; cnt_i = 0; }
    __syncthreads();
    unsigned int w = xw_[t];
    unsigned int e = (w >> 7) & 0xFFu;
    if (e >= 100u && e <= 140u) atomicAdd(&cnt_f, 1);
    unsigned int iw = ei_[2 * t + 1];
    if (iw == 0u) atomicAdd(&cnt_i, 1);
    for (int i = t; i < N_GRAPHS; i += 256) gcnt[i] = 0;
    for (int i = t; i < NB; i += 256) bcnt[i] = 0;
    __syncthreads();
    if (t == 0) {
        flags[0] = (cnt_f < 180) ? 1 : 0;   // 1 => fp32 wire
        flags[1] = (cnt_i >= 128) ? 1 : 0;  // 1 => int64 wire
    }
}

// ---------------- phase A: partition by dst>>9, two-pass blocks ---------------
__global__ __launch_bounds__(256) void k_part(const void* __restrict__ ei,
                                              const void* __restrict__ batch,
                                              int* __restrict__ bcnt,
                                              int* __restrict__ gcnt,
                                              unsigned int* __restrict__ packed,
                                              const int* __restrict__ flags) {
    int I64 = flags[1];
    __shared__ int hist[NB];
    __shared__ int base[NB];
    __shared__ int ghist[N_GRAPHS];        // 4 KB
    __shared__ unsigned int elds[EPB];     // 8 KB: packed words
    __shared__ unsigned char ebkt[EPB];    // 2 KB: bucket ids (0xFF = invalid)
    int t = threadIdx.x;
    if (t < NB) hist[t] = 0;
    for (int i = t; i < N_GRAPHS; i += 256) ghist[i] = 0;
    __syncthreads();
    // batch counting: block covers nodes [blk*128, blk*128+128)
    if (t < 128) {
        int n = blockIdx.x * 128 + t;
        if (n < N_NODES) atomicAdd(&ghist[loadi(batch, n, I64)], 1);
    }
    // edge pass 1: decode once, stage in LDS, bucket counts
    int e0 = blockIdx.x * EPB;
#pragma unroll 4
    for (int it = 0; it < EPB / 256; ++it) {
        int idx = it * 256 + t;
        int e = e0 + idx;
        unsigned int pv = 0u;
        unsigned char bk = 0xFFu;
        if (e < N_EDGES) {
            int sN = loadi(ei, e, I64);
            int d = loadi(ei, (size_t)N_EDGES + e, I64);
            bk = (unsigned char)(d >> SH);
            pv = ((unsigned int)sN << SH) | (unsigned int)(d & 511);
            atomicAdd(&hist[d >> SH], 1);
        }
        elds[idx] = pv;
        ebkt[idx] = bk;
    }
    __syncthreads();
    if (t < NB) {
        base[t] = hist[t] ? atomicAdd(&bcnt[t], hist[t]) : 0;
        hist[t] = 0;   // reuse as pass-2 rank counter
    }
    for (int i = t; i < N_GRAPHS; i += 256)
        if (ghist[i]) atomicAdd(&gcnt[i], ghist[i]);
    __syncthreads();
    // edge pass 2: rank + write from LDS
#pragma unroll 4
    for (int it = 0; it < EPB / 256; ++it) {
        int idx = it * 256 + t;
        unsigned char bk = ebkt[idx];
        if (bk != 0xFFu) {
            unsigned int pv = elds[idx];
            int r = atomicAdd(&hist[bk], 1);
            int pos = base[bk] + r;
            if (pos < BCAP)
                packed[(size_t)bk * BCAP + pos] = pv;
        }
    }
}

// ---------------- fused CSR build + graph scan --------------------------------
// Blocks 0..NBU-1: per-bucket hist + local scan + counting sort + dis + rp2.
// Block NBU: the 1024-entry graph scan (folds the old k_gscan launch).
__global__ __launch_bounds__(512) void k_csr(const unsigned int* __restrict__ packed,
                                             const int* __restrict__ bcnt,
                                             float* __restrict__ dis,
                                             int2* __restrict__ rp2,
                                             int* __restrict__ csr,
                                             const int* __restrict__ gcnt,
                                             int* __restrict__ gptr) {
    __shared__ int hist[512];
    __shared__ int offs[512];
    __shared__ int elds[BCAP];    // 38 KB
    int b = blockIdx.x;
    int t = threadIdx.x;
    if (b == NBU) {
        // graph scan: gcnt (1024) -> gptr
        int a = gcnt[2 * t], bq = gcnt[2 * t + 1];
        int ps = a + bq;
        hist[t] = ps;
        __syncthreads();
        for (int off = 1; off < 512; off <<= 1) {
            int x = (t >= off) ? hist[t - off] : 0;
            __syncthreads();
            hist[t] += x;
            __syncthreads();
        }
        int excl = hist[t] - ps;
        gptr[2 * t] = excl;
        gptr[2 * t + 1] = excl + a;
        if (t == 511) gptr[1024] = hist[511];
        return;
    }
    int n = bcnt[b]; if (n > BCAP) n = BCAP;
    hist[t] = 0;
    __syncthreads();
    const unsigned int* pb = packed + (size_t)b * BCAP;
    for (int i = t; i < n; i += 512)
        atomicAdd(&hist[pb[i] & 511u], 1);
    __syncthreads();
    int c = hist[t];
    offs[t] = c;
    __syncthreads();
    for (int off = 1; off < 512; off <<= 1) {
        int x = (t >= off) ? offs[t - off] : 0;
        __syncthreads();
        offs[t] += x;
        __syncthreads();
    }
    int excl = offs[t] - c;
    int node = (b << SH) + t;
    int base = b * BCAP;
    if (node < N_NODES) {
        dis[node] = rsqrtf((float)c + 1.0f);
        rp2[node] = make_int2(base + excl, base + excl + c);
    }
    __syncthreads();
    offs[t] = excl;               // running scatter counters
    __syncthreads();
    for (int i = t; i < n; i += 512) {
        unsigned int p = pb[i];
        int pos = atomicAdd(&offs[p & 511u], 1);
        if (pos < BCAP) elds[pos] = (int)(p >> SH);
    }
    __syncthreads();
    for (int i = t; i < n; i += 512)
        csr[base + i] = elds[i];
}

// ---------------- MFMA GEMM (layer 1): x[N,128] @ W1 -> slice-major bf16 ------
// out layout: [2 slices][N_NODES][32 feats] bf16, rows pre-scaled by dis.
template <int K>
__global__ __launch_bounds__(256) void k_gemm(const void* __restrict__ x,
                                              const void* __restrict__ W,
                                              const float* __restrict__ dis,
                                              unsigned short* __restrict__ out,  // bf16 bits
                                              const int* __restrict__ flags,
                                              int x_is_f32) {
    int Wf32 = flags[0];
    int xF32 = (x_is_f32 < 0) ? Wf32 : x_is_f32;
    __shared__ unsigned short Wt[64][K + 8];
    __shared__ unsigned short xs[32][K + 8];
    int t = threadIdx.x;
    int wave = t >> 6, lane = t & 63;
    int quad = lane >> 4, l16 = lane & 15;

    for (int id = t; id < 64 * K; id += 256) {
        int k = id >> 6, n = id & 63;
        Wt[n][k] = f2bf(loadf(W, id, Wf32));
    }
    __syncthreads();

    bf16x8 bfrag[K / 32];
#pragma unroll
    for (int c = 0; c < K / 32; ++c)
        bfrag[c] = *reinterpret_cast<bf16x8*>(&Wt[wave * 16 + l16][c * 32 + quad * 8]);

    const int ngroups = (N_NODES + 31) / 32;
    for (int g = blockIdx.x; g < ngroups; g += gridDim.x) {
        __syncthreads();
        int row0 = g * 32;
        for (int cid = t; cid < 4 * K; cid += 256) {
            int rr = cid / (K / 8), c8 = cid % (K / 8);
            int r = row0 + rr;
            u32x4 val = {0u, 0u, 0u, 0u};
            if (r < N_NODES) {
                size_t base = (size_t)r * K + c8 * 8;
                if (xF32) {
                    const u32x4* xp = (const u32x4*)x;
                    u32x4 q0 = xp[base / 4];
                    u32x4 q1 = xp[base / 4 + 1];
                    val.x = f2bf(__uint_as_float(q0.x)) | ((unsigned int)f2bf(__uint_as_float(q0.y)) << 16);
                    val.y = f2bf(__uint_as_float(q0.z)) | ((unsigned int)f2bf(__uint_as_float(q0.w)) << 16);
                    val.z = f2bf(__uint_as_float(q1.x)) | ((unsigned int)f2bf(__uint_as_float(q1.y)) << 16);
                    val.w = f2bf(__uint_as_float(q1.z)) | ((unsigned int)f2bf(__uint_as_float(q1.w)) << 16);
                } else {
                    val = ((const u32x4*)x)[base / 8];
                }
            }
            *reinterpret_cast<u32x4*>(&xs[rr][c8 * 8]) = val;
        }
        __syncthreads();

        f32x4 acc0 = {0.f, 0.f, 0.f, 0.f};
        f32x4 acc1 = {0.f, 0.f, 0.f, 0.f};
#pragma unroll
        for (int c = 0; c < K / 32; ++c) {
            bf16x8 a0 = *reinterpret_cast<bf16x8*>(&xs[l16][c * 32 + quad * 8]);
            bf16x8 a1 = *reinterpret_cast<bf16x8*>(&xs[16 + l16][c * 32 + quad * 8]);
            acc0 = __builtin_amdgcn_mfma_f32_16x16x32_bf16(a0, bfrag[c], acc0, 0, 0, 0);
            acc1 = __builtin_amdgcn_mfma_f32_16x16x32_bf16(a1, bfrag[c], acc1, 0, 0, 0);
        }
        int col = wave * 16 + l16;
        unsigned short* ow = out + (size_t)(col >> 5) * (N_NODES * 32);
        int f = col & 31;
#pragma unroll
        for (int reg = 0; reg < 4; ++reg) {
            int r0 = row0 + quad * 4 + reg;
            if (r0 < N_NODES) ow[(size_t)r0 * 32 + f] = f2bf(acc0[reg] * dis[r0]);
            int r1 = row0 + 16 + quad * 4 + reg;
            if (r1 < N_NODES) ow[(size_t)r1 * 32 + f] = f2bf(acc1[reg] * dis[r1]);
        }
    }
}

// ---------------- layer-1 gather: slice-major in -> node-major hs1 out --------
// R7-proven structure. Epilogue change (R10): out = relu(...)·dis ("hs" scaled
// storage for the fused layers) written NODE-MAJOR [N][64] at 16-B chunk
// (slice*4 + quarter). lane = nodesub(4) x eslot(4) x quarter(4).
__global__ __launch_bounds__(256) void k_gather_sm(const int2* __restrict__ rp2,
                                                   const int* __restrict__ csr,
                                                   const float* __restrict__ dis,
                                                   const unsigned short* __restrict__ xws,
                                                   const void* __restrict__ bias,
                                                   unsigned short* __restrict__ out,
                                                   const int* __restrict__ flags) {
    int F32 = flags[0];
    int blk = blockIdx.x;
    int xcd = blk & 7;
    int s = xcd >> 2;                              // slice 0..1
    int grp = ((blk >> 3) << 2) | (xcd & 3);       // 64-node group
    int wave = threadIdx.x >> 6, lane = threadIdx.x & 63;
    int nodesub = lane >> 4;                       // 0..3
    int eslot = (lane >> 2) & 3;                   // 0..3
    int q = lane & 3;                              // 0..3 (16-B quarter of 64-B row)
    const u32x4* xs4 = (const u32x4*)(xws + (size_t)s * N_NODES * 32);  // row = 4 u32x4
    u32x4* op = (u32x4*)out;                       // node-major [N][64]: 8 u32x4/row
    float bb0 = loadf(bias, s * 32 + q * 8 + 0, F32);
    float bb1 = loadf(bias, s * 32 + q * 8 + 1, F32);
    float bb2 = loadf(bias, s * 32 + q * 8 + 2, F32);
    float bb3 = loadf(bias, s * 32 + q * 8 + 3, F32);
    float bb4 = loadf(bias, s * 32 + q * 8 + 4, F32);
    float bb5 = loadf(bias, s * 32 + q * 8 + 5, F32);
    float bb6 = loadf(bias, s * 32 + q * 8 + 6, F32);
    float bb7 = loadf(bias, s * 32 + q * 8 + 7, F32);
    int wbase = grp * 64 + wave * 16;

    for (int ni = 0; ni < 4; ++ni) {
        int node = wbase + ni * 4 + nodesub;
        int valid = node < N_NODES;
        int2 se = valid ? rp2[node] : make_int2(0, 0);
        int start = se.x, end = se.y;
        float a0 = 0.f, a1 = 0.f, a2 = 0.f, a3 = 0.f;
        float a4 = 0.f, a5 = 0.f, a6 = 0.f, a7 = 0.f;
        int j = start + eslot;
        if (j < end) {
            int src = csr[j];
            for (;;) {
                int jn = j + 4;
                int sn = (jn < end) ? csr[jn] : 0;   // prefetch next index
                u32x4 v = xs4[(size_t)src * 4 + q];
                a0 += bf2f(v.x & 0xFFFFu); a1 += bf2f(v.x >> 16);
                a2 += bf2f(v.y & 0xFFFFu); a3 += bf2f(v.y >> 16);
                a4 += bf2f(v.z & 0xFFFFu); a5 += bf2f(v.z >> 16);
                a6 += bf2f(v.w & 0xFFFFu); a7 += bf2f(v.w >> 16);
                if (jn >= end) break;
                j = jn; src = sn;
            }
        }
#pragma unroll
        for (int off = 4; off <= 8; off <<= 1) {
            a0 += __shfl_down(a0, off, 64); a1 += __shfl_down(a1, off, 64);
            a2 += __shfl_down(a2, off, 64); a3 += __shfl_down(a3, off, 64);
            a4 += __shfl_down(a4, off, 64); a5 += __shfl_down(a5, off, 64);
            a6 += __shfl_down(a6, off, 64); a7 += __shfl_down(a7, off, 64);
        }
        if (((lane & 12) == 0) && valid) {   // eslot == 0
            u32x4 sv = xs4[(size_t)node * 4 + q];   // self row (cache-hot)
            float dn = dis[node];
            float v0 = fmaf(a0 + bf2f(sv.x & 0xFFFFu), dn, bb0);
            float v1 = fmaf(a1 + bf2f(sv.x >> 16),     dn, bb1);
            float v2 = fmaf(a2 + bf2f(sv.y & 0xFFFFu), dn, bb2);
            float v3 = fmaf(a3 + bf2f(sv.y >> 16),     dn, bb3);
            float v4 = fmaf(a4 + bf2f(sv.z & 0xFFFFu), dn, bb4);
            float v5 = fmaf(a5 + bf2f(sv.z >> 16),     dn, bb5);
            float v6 = fmaf(a6 + bf2f(sv.w & 0xFFFFu), dn, bb6);
            float v7 = fmaf(a7 + bf2f(sv.w >> 16),     dn, bb7);
            // hs1 = relu(h1) * dis
            v0 = fmaxf(v0, 0.f) * dn; v1 = fmaxf(v1, 0.f) * dn;
            v2 = fmaxf(v2, 0.f) * dn; v3 = fmaxf(v3, 0.f) * dn;
            v4 = fmaxf(v4, 0.f) * dn; v5 = fmaxf(v5, 0.f) * dn;
            v6 = fmaxf(v6, 0.f) * dn; v7 = fmaxf(v7, 0.f) * dn;
            u32x4 o;
            o.x = (unsigned int)f2bf(v0) | ((unsigned int)f2bf(v1) << 16);
            o.y = (unsigned int)f2bf(v2) | ((unsigned int)f2bf(v3) << 16);
            o.z = (unsigned int)f2bf(v4) | ((unsigned int)f2bf(v5) << 16);
            o.w = (unsigned int)f2bf(v6) | ((unsigned int)f2bf(v7) << 16);
            op[(size_t)node * 8 + s * 4 + q] = o;
        }
    }
}

// ---------------- fused layer: agg-first gather + MFMA GEMM (layers 2,3) ------
// agg(h@W) == agg(h)@W, so: gather g[dst] = dis[dst]*(Σ hs[src] + hs[dst])
// from node-major hs (128-B rows), stage g rows bf16 in LDS, MFMA with W,
// epilogue out = acc + b (relu_scale: relu then *dis -> next hs). Deletes the
// standalone gemm2/gemm3 + one 12.8 MB round-trip per layer; csr read once.
// Block = 64 dst nodes, 4 waves; lane = node2(1b at bit5) x eslot(bits 3-4)
// x oct(bits 0-2): 8 lanes read one full 128-B row.
__global__ __launch_bounds__(256) void k_fgl(const int2* __restrict__ rp2,
                                             const int* __restrict__ csr,
                                             const float* __restrict__ dis,
                                             const unsigned short* __restrict__ hs_in,
                                             const void* __restrict__ W,
                                             const void* __restrict__ bias,
                                             unsigned short* __restrict__ out,
                                             int relu_scale,
                                             const int* __restrict__ flags) {
    int F32 = flags[0];
    __shared__ unsigned short Wt[64][72];
    __shared__ unsigned short xs[64][72];
    int t = threadIdx.x;
    int w = t >> 6, lane = t & 63;
    // stage W[64x64]: Wt[n][k] = W[k*64+n]
    for (int id = t; id < 64 * 64; id += 256) {
        int k = id >> 6, n = id & 63;
        Wt[n][k] = f2bf(loadf(W, id, F32));
    }
    // ---- gather phase ----
    int node2 = lane >> 5;          // 0..1
    int oct = lane & 7;             // 0..7 (16-B chunk of 128-B row)
    const u32x4* xr = (const u32x4*)hs_in;   // row = 8 u32x4
    int wbase = blockIdx.x * 64 + w * 16;
#pragma unroll
    for (int p = 0; p < 8; ++p) {
        int node = wbase + p * 2 + node2;
        int valid = node < N_NODES;
        int2 se = valid ? rp2[node] : make_int2(0, 0);
        float a0 = 0.f, a1 = 0.f, a2 = 0.f, a3 = 0.f;
        float a4 = 0.f, a5 = 0.f, a6 = 0.f, a7 = 0.f;
        int j = se.x + ((lane >> 3) & 3);    // eslot
        if (j < se.y) {
            int src = csr[j];
            for (;;) {
                int jn = j + 4;
                int sn = (jn < se.y) ? csr[jn] : 0;
                u32x4 v = xr[(size_t)src * 8 + oct];
                a0 += bf2f(v.x & 0xFFFFu); a1 += bf2f(v.x >> 16);
                a2 += bf2f(v.y & 0xFFFFu); a3 += bf2f(v.y >> 16);
                a4 += bf2f(v.z & 0xFFFFu); a5 += bf2f(v.z >> 16);
                a6 += bf2f(v.w & 0xFFFFu); a7 += bf2f(v.w >> 16);
                if (jn >= se.y) break;
                j = jn; src = sn;
            }
        }
        // reduce over eslot (lane bits 3-4: offsets 8, 16)
#pragma unroll
        for (int off = 8; off <= 16; off <<= 1) {
            a0 += __shfl_down(a0, off, 64); a1 += __shfl_down(a1, off, 64);
            a2 += __shfl_down(a2, off, 64); a3 += __shfl_down(a3, off, 64);
            a4 += __shfl_down(a4, off, 64); a5 += __shfl_down(a5, off, 64);
            a6 += __shfl_down(a6, off, 64); a7 += __shfl_down(a7, off, 64);
        }
        if ((lane & 24) == 0) {   // eslot == 0: lanes 0-7 and 32-39
            u32x4 sv = {0u, 0u, 0u, 0u};
            float dn = 0.f;
            if (valid) { sv = xr[(size_t)node * 8 + oct]; dn = dis[node]; }
            float v0 = (a0 + bf2f(sv.x & 0xFFFFu)) * dn;
            float v1 = (a1 + bf2f(sv.x >> 16))     * dn;
            float v2 = (a2 + bf2f(sv.y & 0xFFFFu)) * dn;
            float v3 = (a3 + bf2f(sv.y >> 16))     * dn;
            float v4 = (a4 + bf2f(sv.z & 0xFFFFu)) * dn;
            float v5 = (a5 + bf2f(sv.z >> 16))     * dn;
            float v6 = (a6 + bf2f(sv.w & 0xFFFFu)) * dn;
            float v7 = (a7 + bf2f(sv.w >> 16))     * dn;
            u32x4 o;
            o.x = (unsigned int)f2bf(v0) | ((unsigned int)f2bf(v1) << 16);
            o.y = (unsigned int)f2bf(v2) | ((unsigned int)f2bf(v3) << 16);
            o.z = (unsigned int)f2bf(v4) | ((unsigned int)f2bf(v5) << 16);
            o.w = (unsigned int)f2bf(v6) | ((unsigned int)f2bf(v7) << 16);
            *reinterpret_cast<u32x4*>(&xs[w * 16 + p * 2 + node2][oct * 8]) = o;
        }
    }
    __syncthreads();
    // ---- MFMA phase: 64 rows x 64 cols, K=64 ----
    int quad = lane >> 4, l16 = lane & 15;
    bf16x8 bfrag[2];
#pragma unroll
    for (int c = 0; c < 2; ++c)
        bfrag[c] = *reinterpret_cast<bf16x8*>(&Wt[w * 16 + l16][c * 32 + quad * 8]);
    f32x4 acc[4];
#pragma unroll
    for (int rg = 0; rg < 4; ++rg) acc[rg] = (f32x4){0.f, 0.f, 0.f, 0.f};
#pragma unroll
    for (int c = 0; c < 2; ++c) {
#pragma unroll
        for (int rg = 0; rg < 4; ++rg) {
            bf16x8 a = *reinterpret_cast<bf16x8*>(&xs[rg * 16 + l16][c * 32 + quad * 8]);
            acc[rg] = __builtin_amdgcn_mfma_f32_16x16x32_bf16(a, bfrag[c], acc[rg], 0, 0, 0);
        }
    }
    int col = w * 16 + l16;
    float bcol = loadf(bias, col, F32);
    int rbase = blockIdx.x * 64;
#pragma unroll
    for (int rg = 0; rg < 4; ++rg) {
#pragma unroll
        for (int reg = 0; reg < 4; ++reg) {
            int row = rbase + rg * 16 + quad * 4 + reg;
            if (row < N_NODES) {
                float v = acc[rg][reg] + bcol;
                if (relu_scale) v = fmaxf(v, 0.f) * dis[row];
                out[(size_t)row * 64 + col] = f2bf(v);
            }
        }
    }
}

// ---------------- fused mean-pool + linear head (node-major [N][64]) ----------
__global__ __launch_bounds__(256) void k_pool_final(const int* __restrict__ gptr,
                             const unsigned short* __restrict__ h,   // node-major
                             const void* __restrict__ Wl, const void* __restrict__ bl,
                             void* __restrict__ out, const int* __restrict__ flags) {
    int F32 = flags[0];
    __shared__ float part[4];
    int g = blockIdx.x;
    int w = threadIdx.x >> 6;
    int lane = threadIdx.x & 63;
    int nsub = lane >> 5;            // 0..1
    int up = lane & 31;              // u32 feat 0..31
    int s0 = gptr[g], e0 = gptr[g + 1];
    const unsigned int* xr = (const unsigned int*)h;
    float a0 = 0.f, a1 = 0.f;
    for (int n = s0 + w * 2 + nsub; n < e0; n += 8) {
        unsigned int v = xr[(size_t)n * 32 + up];
        a0 += bf2f(v & 0xFFFFu);
        a1 += bf2f(v >> 16);
    }
    a0 += __shfl_down(a0, 32, 64);
    a1 += __shfl_down(a1, 32, 64);
    float v = 0.f;
    if (lane < 32) {
        float cnt = fmaxf((float)(e0 - s0), 1.0f);
        int f = up * 2;
        v = (a0 / cnt) * loadf(Wl, f, F32) + (a1 / cnt) * loadf(Wl, f + 1, F32);
    }
    v += __shfl_down(v, 16, 64);
    v += __shfl_down(v, 8, 64);
    v += __shfl_down(v, 4, 64);
    v += __shfl_down(v, 2, 64);
    v += __shfl_down(v, 1, 64);
    if (lane == 0) part[w] = v;
    __syncthreads();
    if (threadIdx.x == 0) {
        float r = part[0] + part[1] + part[2] + part[3] + loadf(bl, 0, F32);
        if (F32) ((float*)out)[g] = r;
        else     ((__hip_bfloat16*)out)[g] = __float2bfloat16(r);
    }
}

extern "C" void kernel_launch(void* const* d_in, const int* in_sizes, int n_in,
                              void* d_out, int out_size, void* d_ws, size_t ws_size,
                              hipStream_t stream) {
    const void* x     = d_in[0];
    const void* ei    = d_in[1];
    const void* batch = d_in[2];
    const void* W1 = d_in[3];
    const void* b1 = d_in[4];
    const void* W2 = d_in[5];
    const void* b2 = d_in[6];
    const void* W3 = d_in[7];
    const void* b3 = d_in[8];
    const void* Wl = d_in[9];
    const void* bl = d_in[10];

    // workspace layout (~42 MB)
    float* dis   = (float*)d_ws;             // 100352
    int2*  rp2   = (int2*)(dis + 100352);    // 100352 int2 (start,end)
    int*   csr   = (int*)(rp2 + 100352);     // NB*BCAP (per-bucket dense, 7.8 MB)
    int*   gcnt  = csr + NB * BCAP;          // 1024
    int*   gptr  = gcnt + 1024;              // 1056 (needs 1025)
    int*   bcnt  = gptr + 1056;              // 256
    int*   flags = bcnt + 256;               // 16
    unsigned int* packed = (unsigned int*)(flags + 16);    // NB*BCAP (7.8 MB)
    unsigned short* bufA = (unsigned short*)(packed + (size_t)NB * BCAP);  // 12.8 MB
    unsigned short* bufB = bufA + (size_t)N_NODES * 64;                    // 12.8 MB

    const int TB = 256;
    dim3 blk(TB);
    int gGA = 391 * 8;                       // layer-1 gather grid
    int gFG = (N_NODES + 63) / 64;           // 1563 fused-layer blocks

    // init: detect + zero small counters
    k_init<<<1, blk, 0, stream>>>((const unsigned int*)x, (const unsigned int*)ei,
                                  flags, gcnt, bcnt);
    // phase A partition
    k_part<<<(N_EDGES + EPB - 1) / EPB, blk, 0, stream>>>(ei, batch, bcnt, gcnt, packed, flags);
    // fused CSR build + graph scan
    k_csr<<<NBU + 1, 512, 0, stream>>>(packed, bcnt, dis, rp2, csr, gcnt, gptr);

    // ---- layer 1: transform-first (128 -> 64), then gather -> hs1 node-major --
    k_gemm<F_IN><<<1024, blk, 0, stream>>>(x, W1, dis, bufA, flags, -1);
    k_gather_sm<<<gGA, blk, 0, stream>>>(rp2, csr, dis, bufA, b1, bufB, flags);
    // ---- layers 2,3: fused agg-first gather + GEMM ----
    k_fgl<<<gFG, blk, 0, stream>>>(rp2, csr, dis, bufB, W2, b2, bufA, 1, flags);
    k_fgl<<<gFG, blk, 0, stream>>>(rp2, csr, dis, bufA, W3, b3, bufB, 0, flags);

    // ---- pool + head ----
    k_pool_final<<<N_GRAPHS, blk, 0, stream>>>(gptr, bufB, Wl, bl, d_out, flags);
}